// Round 1
// 355.153 us; speedup vs baseline: 1.0591x; 1.0591x over previous
//
#include <hip/hip_runtime.h>
#include <cstddef>

// Problem constants: N=64 state dim, L=16384 seq, BATCH=512, chunk m=128.
static constexpr int RCN = 512 * 128;   // 65536 (row, chunk) pairs

// ws layout (float offsets)
static constexpr size_t WS_W  = 0;       // W[r][i] = (Ab^r Bb)_i, 128x64 fp32
static constexpr size_t WS_G  = 8192;    // fused weights G, 192x128 fp32
static constexpr size_t WS_MD = 32768;   // M = Ab^128, 64x64 DOUBLE (8192 floats)
static constexpr size_t WS_BV = 40960;   // chunk vectors b, RCN x 64 fp32
static constexpr size_t WS_X  = WS_BV + (size_t)RCN * 64;  // chunk states X, RCN x 64 fp32

// ---------------------------------------------------------------------------
// In-place 64x64x64 fp64 matmul in LDS, 4x4 register tile per thread.
//   D = A*B (+ old D if ADD). A rows read per-lane (16-way multicast,
//   conflict-free at stride 65), B row-segments read per-lane (4-way max).
//   8 LDS reads per 16 FMAs vs 17/16 in the untiled version -> ~4x fewer
//   LDS instructions, which is what bounds the single-CU precomp kernel.
// ---------------------------------------------------------------------------
template<bool ADD>
__device__ __forceinline__ void mm64(const double* A, const double* B, double* D,
                                     int tr4, int tc4)
{
  double acc[4][4];
#pragma unroll
  for (int r = 0; r < 4; ++r)
#pragma unroll
    for (int q = 0; q < 4; ++q) acc[r][q] = 0.0;
#pragma unroll 8
  for (int c = 0; c < 64; ++c) {
    double av[4], bv[4];
#pragma unroll
    for (int r = 0; r < 4; ++r) av[r] = A[(tr4 + r) * 65 + c];
#pragma unroll
    for (int q = 0; q < 4; ++q) bv[q] = B[c * 65 + tc4 + q];
#pragma unroll
    for (int r = 0; r < 4; ++r)
#pragma unroll
      for (int q = 0; q < 4; ++q) acc[r][q] = fma(av[r], bv[q], acc[r][q]);
  }
  double old[4][4];
  if (ADD) {
#pragma unroll
    for (int r = 0; r < 4; ++r)
#pragma unroll
      for (int q = 0; q < 4; ++q) old[r][q] = D[(tr4 + r) * 65 + tc4 + q];
  }
  __syncthreads();   // all reads of A/B/D complete before overwrite
#pragma unroll
  for (int r = 0; r < 4; ++r)
#pragma unroll
    for (int q = 0; q < 4; ++q)
      D[(tr4 + r) * 65 + tc4 + q] = ADD ? (old[r][q] + acc[r][q]) : acc[r][q];
  __syncthreads();
}

// ---------------------------------------------------------------------------
// Kernel A: discretize + build all weights. 1 block x 256 threads.
//   Numerics identical to previous version (fp64 Neumann inverse, fp64
//   squaring chain, fp32 W/H storage with fp64 accumulate). Loop nests
//   register-tiled to cut LDS instruction issue ~4x (the measured
//   bottleneck: 150us at VALUBusy 0.12%, LDS-issue bound on 1 CU).
// ---------------------------------------------------------------------------
__global__ __launch_bounds__(256) void k_precomp(
    const float* __restrict__ Ain, const float* __restrict__ Bin,
    const float* __restrict__ Cin, const float* __restrict__ Din,
    const float* __restrict__ LS, float* ws)
{
  __shared__ double Xd[64 * 65];   // hA, then hA^(2^k)
  __shared__ double Pd[64 * 65];   // Z -> N1 -> Ab -> P-chain -> M
  __shared__ float  Wf[128 * 65];  // W[r][i], stride 65
  __shared__ float  Hf[128 * 65];  // H[r][i] = (C Ab^{r+1})_i
  __shared__ float  Kf[128];

  const int t   = threadIdx.x;
  const int tr4 = (t >> 4) << 2;   // row base of 4x4 tile (0..60)
  const int tc4 = (t & 15) << 2;   // col base of 4x4 tile (0..60)

  float*  Wg  = ws + WS_W;
  float*  Gg  = ws + WS_G;
  double* Mgd = (double*)(ws + WS_MD);

  const double step = exp((double)LS[0]);
  const double h = 0.5 * step;

  // X = h*A ; Z = I + X
  for (int idx = t; idx < 4096; idx += 256) {
    int i = idx >> 6, j = idx & 63;
    double a = h * (double)Ain[idx];
    Xd[i * 65 + j] = a;
    Pd[i * 65 + j] = a + ((i == j) ? 1.0 : 0.0);
  }
  __syncthreads();

  // Product-form Neumann: Z <- Z*(I + X^{2^k}), X <- X^2, k = 1..3
  // => Z = sum_{j=0}^{15} X^j ; truncation ||X||^16 <= 0.1^16 = 1e-16.
  for (int k = 0; k < 3; ++k) {
    mm64<false>(Xd, Xd, Xd, tr4, tc4);   // X <- X*X
    mm64<true >(Pd, Xd, Pd, tr4, tc4);   // Z <- Z + Z*X
  }

  // Pd = N1. Bb = step * N1 @ B  -> W[0]
  if (t < 64) {
    double bb = 0.0;
    for (int c = 0; c < 64; ++c) bb = fma(Pd[t * 65 + c], (double)Bin[c], bb);
    Wf[t] = (float)(bb * step);   // W row 0
  }
  __syncthreads();  // all N1 reads complete before overwrite

  // Ab = 2*N1 - I (in place)
  for (int idx = t; idx < 4096; idx += 256) {
    int i = idx >> 6, j = idx & 63;
    Pd[i * 65 + j] = 2.0 * Pd[i * 65 + j] - ((i == j) ? 1.0 : 0.0);
  }
  __syncthreads();

  // H[0] = C @ Ab (column reads of Pd: 2-way, free)
  if (t < 64) {
    double hh = 0.0;
    for (int c = 0; c < 64; ++c) hh = fma((double)Cin[c], Pd[c * 65 + t], hh);
    Hf[t] = (float)hh;
  }
  __syncthreads();

  // Log-doubling: entry invariant P = Ab^n (n = 2^k), W[0..n), H[0..n) valid.
  //   W[n+r][i] = sum_c W[r][c] * P[i][c]
  //   H[n+r][i] = sum_c H[r][c] * P[c][i]
  //   P <- P*P  (shared with the M = Ab^128 chain)
  // Writes (rows >= n) are disjoint from all reads (rows < n, Pd), so the
  // only barriers needed are the ones inside mm64.
  for (int k = 0; k < 7; ++k) {
    const int n = 1 << k;
    if (n <= 8) {
      // small stages: 1 output/thread (cheap; <= 512 outputs)
      for (int o = t; o < (n << 6); o += 256) {
        int r = o >> 6, ii = o & 63;
        double aw = 0.0, ah = 0.0;
#pragma unroll 4
        for (int c = 0; c < 64; ++c) {
          aw = fma(Pd[ii * 65 + c], (double)Wf[r * 65 + c], aw);
          ah = fma((double)Hf[r * 65 + c], Pd[c * 65 + ii], ah);
        }
        Wf[(n + r) * 65 + ii] = (float)aw;
        Hf[(n + r) * 65 + ii] = (float)ah;
      }
    } else if (n == 16) {
      // split: threads 0..127 do W with 2x4 tiles, 128..255 do H.
      const int u  = t & 127;
      const int r2 = (u >> 4) << 1;    // 0..14
      const int i4 = (u & 15) << 2;    // 0..60
      double acc[2][4];
#pragma unroll
      for (int s = 0; s < 2; ++s)
#pragma unroll
        for (int q = 0; q < 4; ++q) acc[s][q] = 0.0;
      if (t < 128) {
#pragma unroll 8
        for (int c = 0; c < 64; ++c) {
          double w0 = (double)Wf[(r2 + 0) * 65 + c];
          double w1 = (double)Wf[(r2 + 1) * 65 + c];
#pragma unroll
          for (int q = 0; q < 4; ++q) {
            double p = Pd[(i4 + q) * 65 + c];
            acc[0][q] = fma(w0, p, acc[0][q]);
            acc[1][q] = fma(w1, p, acc[1][q]);
          }
        }
#pragma unroll
        for (int s = 0; s < 2; ++s)
#pragma unroll
          for (int q = 0; q < 4; ++q)
            Wf[(16 + r2 + s) * 65 + i4 + q] = (float)acc[s][q];
      } else {
#pragma unroll 8
        for (int c = 0; c < 64; ++c) {
          double h0 = (double)Hf[(r2 + 0) * 65 + c];
          double h1 = (double)Hf[(r2 + 1) * 65 + c];
#pragma unroll
          for (int q = 0; q < 4; ++q) {
            double p = Pd[c * 65 + i4 + q];
            acc[0][q] = fma(h0, p, acc[0][q]);
            acc[1][q] = fma(h1, p, acc[1][q]);
          }
        }
#pragma unroll
        for (int s = 0; s < 2; ++s)
#pragma unroll
          for (int q = 0; q < 4; ++q)
            Hf[(16 + r2 + s) * 65 + i4 + q] = (float)acc[s][q];
      }
    } else if (n == 32) {
      // split: threads 0..127 do W with 4x4 tiles, 128..255 do H.
      const int u  = t & 127;
      const int r4 = (u >> 4) << 2;    // 0..28
      const int i4 = (u & 15) << 2;    // 0..60
      double acc[4][4];
#pragma unroll
      for (int r = 0; r < 4; ++r)
#pragma unroll
        for (int q = 0; q < 4; ++q) acc[r][q] = 0.0;
      if (t < 128) {
#pragma unroll 8
        for (int c = 0; c < 64; ++c) {
          double wv[4], pv[4];
#pragma unroll
          for (int r = 0; r < 4; ++r) wv[r] = (double)Wf[(r4 + r) * 65 + c];
#pragma unroll
          for (int q = 0; q < 4; ++q) pv[q] = Pd[(i4 + q) * 65 + c];
#pragma unroll
          for (int r = 0; r < 4; ++r)
#pragma unroll
            for (int q = 0; q < 4; ++q) acc[r][q] = fma(wv[r], pv[q], acc[r][q]);
        }
#pragma unroll
        for (int r = 0; r < 4; ++r)
#pragma unroll
          for (int q = 0; q < 4; ++q)
            Wf[(32 + r4 + r) * 65 + i4 + q] = (float)acc[r][q];
      } else {
#pragma unroll 8
        for (int c = 0; c < 64; ++c) {
          double hv[4], pv[4];
#pragma unroll
          for (int r = 0; r < 4; ++r) hv[r] = (double)Hf[(r4 + r) * 65 + c];
#pragma unroll
          for (int q = 0; q < 4; ++q) pv[q] = Pd[c * 65 + i4 + q];
#pragma unroll
          for (int r = 0; r < 4; ++r)
#pragma unroll
            for (int q = 0; q < 4; ++q) acc[r][q] = fma(hv[r], pv[q], acc[r][q]);
        }
#pragma unroll
        for (int r = 0; r < 4; ++r)
#pragma unroll
          for (int q = 0; q < 4; ++q)
            Hf[(32 + r4 + r) * 65 + i4 + q] = (float)acc[r][q];
      }
    } else {  // n == 64: two full tiled passes, all 256 threads each
      {  // W pass: W[64+r][i] = sum_c W[r][c] * P[i][c]
        double acc[4][4];
#pragma unroll
        for (int r = 0; r < 4; ++r)
#pragma unroll
          for (int q = 0; q < 4; ++q) acc[r][q] = 0.0;
#pragma unroll 8
        for (int c = 0; c < 64; ++c) {
          double wv[4], pv[4];
#pragma unroll
          for (int r = 0; r < 4; ++r) wv[r] = (double)Wf[(tr4 + r) * 65 + c];
#pragma unroll
          for (int q = 0; q < 4; ++q) pv[q] = Pd[(tc4 + q) * 65 + c];
#pragma unroll
          for (int r = 0; r < 4; ++r)
#pragma unroll
            for (int q = 0; q < 4; ++q) acc[r][q] = fma(wv[r], pv[q], acc[r][q]);
        }
#pragma unroll
        for (int r = 0; r < 4; ++r)
#pragma unroll
          for (int q = 0; q < 4; ++q)
            Wf[(64 + tr4 + r) * 65 + tc4 + q] = (float)acc[r][q];
      }
      {  // H pass: H[64+r][i] = sum_c H[r][c] * P[c][i]
        double acc[4][4];
#pragma unroll
        for (int r = 0; r < 4; ++r)
#pragma unroll
          for (int q = 0; q < 4; ++q) acc[r][q] = 0.0;
#pragma unroll 8
        for (int c = 0; c < 64; ++c) {
          double hv[4], pv[4];
#pragma unroll
          for (int r = 0; r < 4; ++r) hv[r] = (double)Hf[(tr4 + r) * 65 + c];
#pragma unroll
          for (int q = 0; q < 4; ++q) pv[q] = Pd[c * 65 + tc4 + q];
#pragma unroll
          for (int r = 0; r < 4; ++r)
#pragma unroll
            for (int q = 0; q < 4; ++q) acc[r][q] = fma(hv[r], pv[q], acc[r][q]);
        }
#pragma unroll
        for (int r = 0; r < 4; ++r)
#pragma unroll
          for (int q = 0; q < 4; ++q)
            Hf[(64 + tr4 + r) * 65 + tc4 + q] = (float)acc[r][q];
      }
    }
    // P <- P*P (barriers inside also order the W/H writes vs next stage reads)
    mm64<false>(Pd, Pd, Pd, tr4, tc4);
  }

  // Pd = Ab^128 = M (fp64) -> global for k_scan
  for (int idx = t; idx < 4096; idx += 256)
    Mgd[idx] = Pd[(idx >> 6) * 65 + (idx & 63)];

  // K[r] = C . W[r]
  if (t < 128) {
    double s = 0.0;
    for (int c = 0; c < 64; ++c) s = fma((double)Cin[c], (double)Wf[t * 65 + c], s);
    Kf[t] = (float)s;
  }
  __syncthreads();

  // W -> global (dense 64-stride for k_chunkvec)
  for (int idx = t; idx < 8192; idx += 256)
    Wg[idx] = Wf[(idx >> 6) * 65 + (idx & 63)];

  // G Toeplitz part: G[k][r] = K[r-k] (r>=k) + D*(k==r)
  const float Dval = Din[0];
  for (int idx = t; idx < 16384; idx += 256) {
    int k = idx >> 7, r = idx & 127;
    float v = (r >= k) ? Kf[r - k] : 0.f;
    if (k == r) v += Dval;
    Gg[idx] = v;
  }
  // G cross-chunk part: G[128+i][r] = H[r][i]
  for (int idx = t; idx < 8192; idx += 256) {
    int i = idx >> 7, r = idx & 127;
    Gg[(128 + i) * 128 + r] = Hf[r * 65 + i];
  }
}

// ---------------------------------------------------------------------------
// Kernel B: chunk input vectors  b[rc][i] = sum_k u[rc][k] * W[127-k][i]
// GEMM M=65536, N=64, K=128. Block = 128 rc-rows, 128 threads, 8x8 tiles.
// ---------------------------------------------------------------------------
__global__ __launch_bounds__(128) void k_chunkvec(
    const float* __restrict__ u, const float* __restrict__ Wg,
    float* __restrict__ bout)
{
  __shared__ float As[32 * 132];  // [kk][rcl], transposed u slice
  __shared__ float Bs[32 * 68];   // [kk][i]
  const int t = threadIdx.x;
  const int rc0 = blockIdx.x << 7;
  const int trow = (t >> 3) << 3;
  const int tcol = (t & 7) << 3;
  float acc[8][8];
#pragma unroll
  for (int i = 0; i < 8; ++i)
#pragma unroll
    for (int j = 0; j < 8; ++j) acc[i][j] = 0.f;

  for (int sl = 0; sl < 4; ++sl) {
    for (int it = t; it < 1024; it += 128) {
      int rcl = it >> 3, k4 = (it & 7) << 2;
      float4 v = *(const float4*)&u[((size_t)(rc0 + rcl) << 7) + (sl << 5) + k4];
      As[(k4 + 0) * 132 + rcl] = v.x;
      As[(k4 + 1) * 132 + rcl] = v.y;
      As[(k4 + 2) * 132 + rcl] = v.z;
      As[(k4 + 3) * 132 + rcl] = v.w;
    }
    for (int it = t; it < 512; it += 128) {
      int kk = it >> 4, i4 = (it & 15) << 2;
      *(float4*)&Bs[kk * 68 + i4] =
          *(const float4*)&Wg[((size_t)(127 - ((sl << 5) + kk)) << 6) + i4];
    }
    __syncthreads();
#pragma unroll 4
    for (int kk = 0; kk < 32; ++kk) {
      float av[8], bv[8];
      *(float4*)&av[0] = *(const float4*)&As[kk * 132 + trow];
      *(float4*)&av[4] = *(const float4*)&As[kk * 132 + trow + 4];
      *(float4*)&bv[0] = *(const float4*)&Bs[kk * 68 + tcol];
      *(float4*)&bv[4] = *(const float4*)&Bs[kk * 68 + tcol + 4];
#pragma unroll
      for (int i = 0; i < 8; ++i)
#pragma unroll
        for (int j = 0; j < 8; ++j) acc[i][j] = fmaf(av[i], bv[j], acc[i][j]);
    }
    __syncthreads();
  }
#pragma unroll
  for (int i = 0; i < 8; ++i) {
    size_t base = ((size_t)(rc0 + trow + i) << 6) + tcol;
    *(float4*)&bout[base]     = make_float4(acc[i][0], acc[i][1], acc[i][2], acc[i][3]);
    *(float4*)&bout[base + 4] = make_float4(acc[i][4], acc[i][5], acc[i][6], acc[i][7]);
  }
}

// ---------------------------------------------------------------------------
// Kernel C: per-row chunk-state scan in fp64. X_0 = 0; X_{j+1} = M X_j + b_j.
// ---------------------------------------------------------------------------
__global__ __launch_bounds__(256) void k_scan(
    const double* __restrict__ Mg, const float* __restrict__ bv,
    float* __restrict__ Xg)
{
  __shared__ double xs[64];
  __shared__ double part[3 * 64];
  const int t = threadIdx.x;
  const int i = t & 63, q = t >> 6;   // q is wave-uniform
  double Mr[16];
#pragma unroll
  for (int c = 0; c < 16; ++c) Mr[c] = Mg[((size_t)i << 6) + (q << 4) + c];
  const float* br = bv + ((size_t)blockIdx.x << 13);
  float* Xr = Xg + ((size_t)blockIdx.x << 13);
  if (t < 64) xs[t] = 0.0;
  __syncthreads();
  for (int j = 0; j < 128; ++j) {
    double s0 = 0, s1 = 0, s2 = 0, s3 = 0;
#pragma unroll
    for (int c = 0; c < 16; c += 4) {   // xs reads are wave-uniform broadcasts
      s0 = fma(Mr[c + 0], xs[(q << 4) + c + 0], s0);
      s1 = fma(Mr[c + 1], xs[(q << 4) + c + 1], s1);
      s2 = fma(Mr[c + 2], xs[(q << 4) + c + 2], s2);
      s3 = fma(Mr[c + 3], xs[(q << 4) + c + 3], s3);
    }
    double ps = (s0 + s1) + (s2 + s3);
    if (q) part[((q - 1) << 6) + i] = ps;
    __syncthreads();
    if (q == 0) {
      double xold = xs[i];
      Xr[(j << 6) + i] = (float)xold;                 // state at chunk start
      xs[i] = (double)br[(j << 6) + i] + ps + part[i] + part[64 + i] + part[128 + i];
    }
    __syncthreads();
  }
}

// ---------------------------------------------------------------------------
// Kernel D: main output GEMM. y[rc][r] = sum_{k<128} u[rc][k] G[k][r]
//                                       + sum_i X[rc][i] G[128+i][r]
// ---------------------------------------------------------------------------
__global__ __launch_bounds__(256) void k_main(
    const float* __restrict__ u, const float* __restrict__ Xg,
    const float* __restrict__ Gg, float* __restrict__ out)
{
  __shared__ float As[32 * 132];  // [kk][rcl]
  __shared__ float Bs[32 * 132];  // [kk][r]
  const int t = threadIdx.x;
  const int rc0 = blockIdx.x << 7;
  const int trow = (t >> 4) << 3;
  const int tcol = (t & 15) << 3;
  float acc[8][8];
#pragma unroll
  for (int i = 0; i < 8; ++i)
#pragma unroll
    for (int j = 0; j < 8; ++j) acc[i][j] = 0.f;

  for (int sl = 0; sl < 6; ++sl) {
    const int k0 = sl << 5;
    for (int it = t; it < 1024; it += 256) {
      int rcl = it >> 3, k4 = (it & 7) << 2;
      int kg = k0 + k4;
      float4 v;
      if (kg < 128)
        v = *(const float4*)&u[((size_t)(rc0 + rcl) << 7) + kg];
      else
        v = *(const float4*)&Xg[((size_t)(rc0 + rcl) << 6) + (kg - 128)];
      As[(k4 + 0) * 132 + rcl] = v.x;
      As[(k4 + 1) * 132 + rcl] = v.y;
      As[(k4 + 2) * 132 + rcl] = v.z;
      As[(k4 + 3) * 132 + rcl] = v.w;
    }
    for (int it = t; it < 1024; it += 256) {
      int kk = it >> 5, r4 = (it & 31) << 2;
      *(float4*)&Bs[kk * 132 + r4] = *(const float4*)&Gg[(size_t)(k0 + kk) * 128 + r4];
    }
    __syncthreads();
#pragma unroll 4
    for (int kk = 0; kk < 32; ++kk) {
      float av[8], bv[8];
      *(float4*)&av[0] = *(const float4*)&As[kk * 132 + trow];
      *(float4*)&av[4] = *(const float4*)&As[kk * 132 + trow + 4];
      *(float4*)&bv[0] = *(const float4*)&Bs[kk * 132 + tcol];
      *(float4*)&bv[4] = *(const float4*)&Bs[kk * 132 + tcol + 4];
#pragma unroll
      for (int i = 0; i < 8; ++i)
#pragma unroll
        for (int j = 0; j < 8; ++j) acc[i][j] = fmaf(av[i], bv[j], acc[i][j]);
    }
    __syncthreads();
  }
#pragma unroll
  for (int i = 0; i < 8; ++i) {
    size_t base = ((size_t)(rc0 + trow + i) << 7) + tcol;
    *(float4*)&out[base]     = make_float4(acc[i][0], acc[i][1], acc[i][2], acc[i][3]);
    *(float4*)&out[base + 4] = make_float4(acc[i][4], acc[i][5], acc[i][6], acc[i][7]);
  }
}

// ---------------------------------------------------------------------------
extern "C" void kernel_launch(void* const* d_in, const int* in_sizes, int n_in,
                              void* d_out, int out_size, void* d_ws, size_t ws_size,
                              hipStream_t stream) {
  (void)in_sizes; (void)n_in; (void)out_size; (void)ws_size;
  const float* u  = (const float*)d_in[0];
  const float* A  = (const float*)d_in[1];
  const float* Bv = (const float*)d_in[2];
  const float* Cv = (const float*)d_in[3];
  const float* Dv = (const float*)d_in[4];
  const float* ls = (const float*)d_in[5];
  float* out = (float*)d_out;
  float* ws  = (float*)d_ws;

  k_precomp<<<1, 256, 0, stream>>>(A, Bv, Cv, Dv, ls, ws);
  k_chunkvec<<<512, 128, 0, stream>>>(u, ws + WS_W, ws + WS_BV);
  k_scan<<<512, 256, 0, stream>>>((const double*)(ws + WS_MD), ws + WS_BV, ws + WS_X);
  k_main<<<512, 256, 0, stream>>>(u, ws + WS_X, ws + WS_G, out);
}